// Round 3
// baseline (428.568 us; speedup 1.0000x reference)
//
#include <hip/hip_runtime.h>
#include <cstdint>

typedef unsigned short u16;
typedef __attribute__((ext_vector_type(4))) unsigned short u16x4;
typedef __attribute__((ext_vector_type(8))) short short8;
typedef __attribute__((ext_vector_type(4))) float f32x4;

#define DI 512
#define CIN 1024
#define NPIX 4096   // 64*64
#define MPIX 1024   // 32*32

__device__ __forceinline__ float bf2f(u16 u) {
  union { unsigned int i; float f; } v; v.i = ((unsigned int)u) << 16; return v.f;
}
__device__ __forceinline__ u16 f2bf(float f) {
  union { float f; unsigned int i; } v; v.f = f;
  unsigned int r = v.i + 0x7fffu + ((v.i >> 16) & 1u);
  return (u16)(r >> 16);
}
__device__ __forceinline__ void unpack8(uint4 v, float* f) {
  union { unsigned int i; float f; } u;
  u.i = v.x << 16;          f[0] = u.f;
  u.i = v.x & 0xffff0000u;  f[1] = u.f;
  u.i = v.y << 16;          f[2] = u.f;
  u.i = v.y & 0xffff0000u;  f[3] = u.f;
  u.i = v.z << 16;          f[4] = u.f;
  u.i = v.z & 0xffff0000u;  f[5] = u.f;
  u.i = v.w << 16;          f[6] = u.f;
  u.i = v.w & 0xffff0000u;  f[7] = u.f;
}

// ---------------- f32 -> bf16 convert (weights) ----------------
__global__ __launch_bounds__(256) void cvt_kernel(const float* __restrict__ src,
                                                  u16* __restrict__ dst, int n4) {
  int i = blockIdx.x * 256 + threadIdx.x;
  if (i < n4) {
    float4 v = *(const float4*)(src + (long)i * 4);
    u16x4 w;
    w[0] = f2bf(v.x); w[1] = f2bf(v.y); w[2] = f2bf(v.z); w[3] = f2bf(v.w);
    *(u16x4*)(dst + (long)i * 4) = w;
  }
}

// ---------------- x [b][c][n] f32 -> x_T [b][n][c] bf16 ----------------
__global__ __launch_bounds__(256) void transpose_kernel(const float* __restrict__ x,
                                                        u16* __restrict__ xT) {
  __shared__ u16 tile[64][72];
  const int b = blockIdx.z;
  const int n0 = blockIdx.x * 64, c0 = blockIdx.y * 64;
  const float* xb = x + (long)b * CIN * NPIX;
  u16* xTb = xT + (long)b * NPIX * CIN;
  const int t = threadIdx.x;
  const int tc = t >> 4, tn = (t & 15) * 4;
  #pragma unroll
  for (int i = 0; i < 4; i++) {
    int c = tc + i * 16;
    float4 v = *(const float4*)(xb + (long)(c0 + c) * NPIX + n0 + tn);
    tile[c][tn + 0] = f2bf(v.x);
    tile[c][tn + 1] = f2bf(v.y);
    tile[c][tn + 2] = f2bf(v.z);
    tile[c][tn + 3] = f2bf(v.w);
  }
  __syncthreads();
  const int tn2 = t >> 4, tc2 = (t & 15) * 4;
  #pragma unroll
  for (int i = 0; i < 4; i++) {
    int n = tn2 + i * 16;
    u16x4 w;
    w[0] = tile[tc2 + 0][n];
    w[1] = tile[tc2 + 1][n];
    w[2] = tile[tc2 + 2][n];
    w[3] = tile[tc2 + 3][n];
    *(u16x4*)(xTb + (long)(n0 + n) * CIN + c0 + tc2) = w;
  }
}

// ---------------- 2x2 maxpool in transposed layout ----------------
__global__ __launch_bounds__(256) void pool_kernel(const u16* __restrict__ xT,
                                                   u16* __restrict__ poolT) {
  const int idx = blockIdx.x * 256 + threadIdx.x;
  const int cc = (idx & 127) * 8;
  const int m = (idx >> 7) & 1023;
  const int b = idx >> 17;
  const int i = m >> 5, j = m & 31;
  const int n1 = (i * 2) * 64 + j * 2;
  const u16* base = xT + (long)b * NPIX * CIN + cc;
  uint4 v0 = *(const uint4*)(base + (long)(n1) * CIN);
  uint4 v1 = *(const uint4*)(base + (long)(n1 + 1) * CIN);
  uint4 v2 = *(const uint4*)(base + (long)(n1 + 64) * CIN);
  uint4 v3 = *(const uint4*)(base + (long)(n1 + 65) * CIN);
  float f0[8], f1[8], f2[8], f3[8];
  unpack8(v0, f0); unpack8(v1, f1); unpack8(v2, f2); unpack8(v3, f3);
  u16 r[8] __attribute__((aligned(16)));
  #pragma unroll
  for (int k = 0; k < 8; k++) {
    float mx = fmaxf(fmaxf(f0[k], f1[k]), fmaxf(f2[k], f3[k]));
    r[k] = f2bf(mx);
  }
  *(uint4*)(poolT + ((long)b * MPIX + m) * CIN + cc) = *(uint4*)r;
}

// ---------------- GEMM: C[M][N] = A[M][K] * B[N][K]^T ----
// OM: 0 = bf16 plain, 1 = bf16 transposed [N][M], 2 = f32 plain.
// epilogue: v = acc*scale; if CS v *= cs[col]; if SHIFT v -= shift[row];
//           if BIAS v += bias[row]
template<int OM, bool HAS_BIAS, bool HAS_CS, bool HAS_SHIFT>
__global__ __launch_bounds__(256)
void gemm_tn(const u16* __restrict__ A, const u16* __restrict__ B,
             void* __restrict__ Cv,
             const float* __restrict__ bias, long sBias,
             const float* __restrict__ cs, long sCS,
             const float* __restrict__ shift, long sShift,
             float scale, int M, int N, int K, long sA, long sB, long sC)
{
  A += blockIdx.z * sA;
  B += blockIdx.z * sB;
  if (HAS_BIAS) bias += blockIdx.z * sBias;
  if (HAS_CS) cs += blockIdx.z * sCS;
  if (HAS_SHIFT) shift += blockIdx.z * sShift;
  const int bm = blockIdx.y * 128;
  const int bn = blockIdx.x * 128;
  __shared__ u16 As[128][72];
  __shared__ u16 Bs[128][72];
  const int tid = threadIdx.x;
  const int lane = tid & 63;
  const int wave = tid >> 6;
  const int wm = (wave >> 1) * 64;
  const int wn = (wave & 1) * 64;
  const int lr = lane & 15;          // frag row (A) / col (B,D)
  const int lk = (lane >> 4) * 8;    // k-octet
  f32x4 acc[4][4] = {};

  const u16* Arow = A + (long)bm * K;
  const u16* Brow = B + (long)bn * K;
  const int r0 = tid >> 3;
  const int kc = (tid & 7) * 8;

  for (int kt = 0; kt < K; kt += 64) {
    __syncthreads();
    #pragma unroll
    for (int i = 0; i < 4; i++) {
      int row = r0 + i * 32;
      *(uint4*)&As[row][kc] = *(const uint4*)(Arow + (long)row * K + kt + kc);
      *(uint4*)&Bs[row][kc] = *(const uint4*)(Brow + (long)row * K + kt + kc);
    }
    __syncthreads();
    #pragma unroll
    for (int kk = 0; kk < 2; kk++) {
      short8 av[4], bv[4];
      #pragma unroll
      for (int mi = 0; mi < 4; mi++)
        av[mi] = *(const short8*)&As[wm + mi * 16 + lr][kk * 32 + lk];
      #pragma unroll
      for (int ni = 0; ni < 4; ni++)
        bv[ni] = *(const short8*)&Bs[wn + ni * 16 + lr][kk * 32 + lk];
      #pragma unroll
      for (int mi = 0; mi < 4; mi++) {
        #pragma unroll
        for (int ni = 0; ni < 4; ni++)
          acc[mi][ni] = __builtin_amdgcn_mfma_f32_16x16x32_bf16(
              av[mi], bv[ni], acc[mi][ni], 0, 0, 0);
      }
    }
  }

  const int dr = (lane >> 4) * 4;
  #pragma unroll
  for (int mi = 0; mi < 4; mi++) {
    const int rowb = bm + wm + mi * 16 + dr;
    float bvs[4] = {0.f, 0.f, 0.f, 0.f};
    float shv[4] = {0.f, 0.f, 0.f, 0.f};
    if (HAS_BIAS) {
      #pragma unroll
      for (int r = 0; r < 4; r++) bvs[r] = bias[rowb + r];
    }
    if (HAS_SHIFT) {
      #pragma unroll
      for (int r = 0; r < 4; r++) shv[r] = shift[rowb + r];
    }
    #pragma unroll
    for (int ni = 0; ni < 4; ni++) {
      const int col = bn + wn + ni * 16 + lr;
      const float csv = HAS_CS ? cs[col] : 1.0f;
      float v[4];
      #pragma unroll
      for (int r = 0; r < 4; r++) {
        float t = acc[mi][ni][r] * scale;
        if (HAS_CS) t *= csv;
        if (HAS_SHIFT) t -= shv[r];
        if (HAS_BIAS) t += bvs[r];
        v[r] = t;
      }
      if (OM == 1) {
        u16* C = (u16*)Cv + blockIdx.z * sC;
        u16x4 w;
        #pragma unroll
        for (int r = 0; r < 4; r++) w[r] = f2bf(v[r]);
        *(u16x4*)(C + (long)col * M + rowb) = w;
      } else if (OM == 0) {
        u16* C = (u16*)Cv + blockIdx.z * sC;
        #pragma unroll
        for (int r = 0; r < 4; r++)
          C[(long)(rowb + r) * N + col] = f2bf(v[r]);
      } else {
        float* C = (float*)Cv + blockIdx.z * sC;
        #pragma unroll
        for (int r = 0; r < 4; r++)
          C[(long)(rowb + r) * N + col] = v[r];
      }
    }
  }
}

// ---------------- row softmax (unnormalized): one WAVE per row of 1024 ----
__global__ __launch_bounds__(256) void softmax_kernel(const u16* __restrict__ s,
                                                      u16* __restrict__ e_out,
                                                      float* __restrict__ inv_out) {
  const int row = blockIdx.x * 4 + (threadIdx.x >> 6);
  const int lane = threadIdx.x & 63;
  const long base = (long)row * MPIX + lane * 16;
  uint4 va = *(const uint4*)(s + base);
  uint4 vb = *(const uint4*)(s + base + 8);
  float f[16];
  unpack8(va, f); unpack8(vb, f + 8);
  float mx = f[0];
  #pragma unroll
  for (int j = 1; j < 16; j++) mx = fmaxf(mx, f[j]);
  #pragma unroll
  for (int off = 32; off > 0; off >>= 1) mx = fmaxf(mx, __shfl_xor(mx, off));
  float e[16], sum = 0.f;
  #pragma unroll
  for (int j = 0; j < 16; j++) { e[j] = expf(f[j] - mx); sum += e[j]; }
  #pragma unroll
  for (int off = 32; off > 0; off >>= 1) sum += __shfl_xor(sum, off);
  if (lane == 0) inv_out[row] = 1.0f / sum;
  u16 r[16] __attribute__((aligned(16)));
  #pragma unroll
  for (int j = 0; j < 16; j++) r[j] = f2bf(e[j]);
  *(uint4*)(e_out + base) = *(uint4*)r;
  *(uint4*)(e_out + base + 8) = *(uint4*)(r + 8);
}

// ---------------- gbar[b][d] = mean over m of g_n[b][d][:] ----------------
__global__ __launch_bounds__(256) void gbar_kernel(const u16* __restrict__ g_n,
                                                   float* __restrict__ gbar) {
  const int row = blockIdx.x * 4 + (threadIdx.x >> 6);   // 0..4095 = b*512+d
  const int lane = threadIdx.x & 63;
  const long base = (long)row * MPIX + lane * 16;
  uint4 va = *(const uint4*)(g_n + base);
  uint4 vb = *(const uint4*)(g_n + base + 8);
  float f[16];
  unpack8(va, f); unpack8(vb, f + 8);
  float s = 0.f;
  #pragma unroll
  for (int j = 0; j < 16; j++) s += f[j];
  #pragma unroll
  for (int off = 32; off > 0; off >>= 1) s += __shfl_xor(s, off);
  if (lane == 0) gbar[row] = s * (1.0f / 1024.0f);
}

// ------- c0[b][c] = out_b[c] + sum_d out_w_f32[c][d]*gbar[b][d] ----------
__global__ __launch_bounds__(256) void c0_kernel(const float* __restrict__ out_w,
                                                 const float* __restrict__ out_b,
                                                 const float* __restrict__ gbar,
                                                 float* __restrict__ c0) {
  const int idx = blockIdx.x * 4 + (threadIdx.x >> 6);   // 0..8191 = b*1024+c
  const int lane = threadIdx.x & 63;
  const int b = idx >> 10, c = idx & 1023;
  const int d0 = lane * 8;
  float4 w0 = *(const float4*)(out_w + (long)c * DI + d0);
  float4 w1 = *(const float4*)(out_w + (long)c * DI + d0 + 4);
  float4 g0 = *(const float4*)(gbar + (long)b * DI + d0);
  float4 g1 = *(const float4*)(gbar + (long)b * DI + d0 + 4);
  float s = w0.x * g0.x + w0.y * g0.y + w0.z * g0.z + w0.w * g0.w
          + w1.x * g1.x + w1.y * g1.y + w1.z * g1.z + w1.w * g1.w;
  #pragma unroll
  for (int off = 32; off > 0; off >>= 1) s += __shfl_xor(s, off);
  if (lane == 0) c0[idx] = out_b[c] + s;
}

// ---------------- BN stats on f32 y: one block per channel ---------------
__global__ __launch_bounds__(256) void stats_kernel(const float* __restrict__ y,
                                                    float* __restrict__ stats) {
  const int co = blockIdx.x;
  const int t = threadIdx.x;
  float s = 0.f, s2 = 0.f;
  for (int b = 0; b < 8; b++) {
    const long base = ((long)b * 1024 + co) * 4096;
    #pragma unroll
    for (int i = 0; i < 4; i++) {
      float4 v = *(const float4*)(y + base + (long)(i * 256 + t) * 4);
      s += v.x + v.y + v.z + v.w;
      s2 += v.x * v.x + v.y * v.y + v.z * v.z + v.w * v.w;
    }
  }
  #pragma unroll
  for (int off = 32; off > 0; off >>= 1) {
    s += __shfl_xor(s, off);
    s2 += __shfl_xor(s2, off);
  }
  __shared__ float rs[4], rq[4];
  if ((t & 63) == 0) { rs[t >> 6] = s; rq[t >> 6] = s2; }
  __syncthreads();
  if (t == 0) {
    stats[co] = rs[0] + rs[1] + rs[2] + rs[3];
    stats[1024 + co] = rq[0] + rq[1] + rq[2] + rq[3];
  }
}

// ---------------- BN apply + residual (f32 y) ----------------
__global__ __launch_bounds__(256) void final_kernel(const float* __restrict__ y,
    const float* __restrict__ x, const float* __restrict__ stats,
    const float* __restrict__ bnw, const float* __restrict__ bnb,
    float* __restrict__ out) {
  const int bc = blockIdx.x;
  const int co = bc & 1023;
  const float mean = stats[co] * (1.0f / 32768.0f);
  const float var = stats[1024 + co] * (1.0f / 32768.0f) - mean * mean;
  const float inv = rsqrtf(var + 1e-5f) * bnw[co];
  const float add = bnb[co] - mean * inv;
  const long base = (long)bc * 4096;
  const int t = threadIdx.x;
  #pragma unroll
  for (int i = 0; i < 4; i++) {
    const long off = base + (long)(i * 256 + t) * 4;
    float4 v = *(const float4*)(y + off);
    const float4 xv = *(const float4*)(x + off);
    float4 o;
    o.x = v.x * inv + add + xv.x;
    o.y = v.y * inv + add + xv.y;
    o.z = v.z * inv + add + xv.z;
    o.w = v.w * inv + add + xv.w;
    *(float4*)(out + off) = o;
  }
}

extern "C" void kernel_launch(void* const* d_in, const int* in_sizes, int n_in,
                              void* d_out, int out_size, void* d_ws, size_t ws_size,
                              hipStream_t stream) {
  (void)in_sizes; (void)n_in; (void)out_size; (void)ws_size;
  const float* x       = (const float*)d_in[0];
  const float* theta_w = (const float*)d_in[1];
  const float* theta_b = (const float*)d_in[2];
  const float* phi_w   = (const float*)d_in[3];
  const float* phi_b   = (const float*)d_in[4];
  const float* g_w     = (const float*)d_in[5];
  const float* g_b     = (const float*)d_in[6];
  const float* out_w   = (const float*)d_in[7];
  const float* out_b   = (const float*)d_in[8];
  const float* bn_w    = (const float*)d_in[9];
  const float* bn_b    = (const float*)d_in[10];
  float* out = (float*)d_out;
  char* ws = (char*)d_ws;
  const size_t MB = 1024 * 1024;

  // workspace layout
  u16* xT     = (u16*)(ws + 0 * MB);       // 64MB; later: e (softmax out); later: y f32 [0,128MB)
  u16* poolT  = (u16*)(ws + 64 * MB);      // 16MB
  u16* w_th   = (u16*)(ws + 80 * MB);      // 1MB
  u16* w_ph   = (u16*)(ws + 81 * MB);      // 1MB
  u16* w_g    = (u16*)(ws + 82 * MB);      // 1MB
  u16* thetaT = (u16*)(ws + 84 * MB);      // 32MB
  u16* phiT   = (u16*)(ws + 116 * MB);     // 8MB
  u16* g_n    = (u16*)(ws + 124 * MB);     // 8MB
  u16* scores = (u16*)(ws + 132 * MB);     // 64MB
  u16* tT     = (u16*)(ws + 196 * MB);     // 32MB (delta-t bf16)
  u16* w_out  = (u16*)(ws + 228 * MB);     // 1MB
  float* inv_s = (float*)(ws + 229 * MB);            // 128KB
  float* gbar  = (float*)(ws + 229 * MB + 131072);   // 16KB
  float* c0b   = (float*)(ws + 229 * MB + 147456);   // 32KB
  float* stats = (float*)(ws + 229 * MB + 180224);   // 8KB
  u16* e = xT;                // alias: x_T dead after theta GEMM
  float* y = (float*)ws;      // alias [0,128MB): all dead before y-GEMM

  // 1. weights -> bf16
  cvt_kernel<<<512, 256, 0, stream>>>(theta_w, w_th, 131072);
  cvt_kernel<<<512, 256, 0, stream>>>(phi_w,   w_ph, 131072);
  cvt_kernel<<<512, 256, 0, stream>>>(g_w,     w_g,  131072);
  cvt_kernel<<<512, 256, 0, stream>>>(out_w,   w_out, 131072);
  // 2. x -> x_T bf16 ; 3. pool
  transpose_kernel<<<dim3(64, 16, 8), 256, 0, stream>>>(x, xT);
  pool_kernel<<<4096, 256, 0, stream>>>(xT, poolT);
  // 4. theta -> theta_T [b][4096][512]
  gemm_tn<1, true, false, false><<<dim3(32, 4, 8), 256, 0, stream>>>(
      w_th, xT, thetaT, theta_b, 0L, nullptr, 0L, nullptr, 0L,
      1.0f, 512, 4096, 1024, 0L, (long)NPIX * CIN, (long)NPIX * DI);
  // 5. phi -> phi_T [b][1024][512]
  gemm_tn<1, true, false, false><<<dim3(8, 4, 8), 256, 0, stream>>>(
      w_ph, poolT, phiT, phi_b, 0L, nullptr, 0L, nullptr, 0L,
      1.0f, 512, 1024, 1024, 0L, (long)MPIX * CIN, (long)MPIX * DI);
  // 6. g -> g_n [b][512][1024]
  gemm_tn<0, true, false, false><<<dim3(8, 4, 8), 256, 0, stream>>>(
      w_g, poolT, g_n, g_b, 0L, nullptr, 0L, nullptr, 0L,
      1.0f, 512, 1024, 1024, 0L, (long)MPIX * CIN, (long)DI * MPIX);
  // 6b. gbar[b][d] ; c0[b][c] (f32 path for the constant part of t)
  gbar_kernel<<<1024, 256, 0, stream>>>(g_n, gbar);
  c0_kernel<<<2048, 256, 0, stream>>>(out_w, out_b, gbar, c0b);
  // 7. scores[n][m] = theta_T * phi_T^T, scaled; bf16 [b][4096][1024]
  gemm_tn<0, false, false, false><<<dim3(8, 32, 8), 256, 0, stream>>>(
      thetaT, phiT, scores, nullptr, 0L, nullptr, 0L, nullptr, 0L,
      0.044194173824159216f, 4096, 1024, 512,
      (long)NPIX * DI, (long)MPIX * DI, (long)NPIX * MPIX);
  // 8. unnormalized softmax rows -> e (aliases xT), inv_s[b*4096+n]
  softmax_kernel<<<8192, 256, 0, stream>>>(scores, e, inv_s);
  // 9. delta-t[d][n] = (g_n * e^T)*inv_s[n] - gbar[d] -> tT bf16 [b][4096][512]
  gemm_tn<1, false, true, true><<<dim3(32, 4, 8), 256, 0, stream>>>(
      g_n, e, tT, nullptr, 0L, inv_s, 4096L, gbar, 512L,
      1.0f, 512, 4096, 1024,
      (long)DI * MPIX, (long)NPIX * MPIX, (long)NPIX * DI);
  // 10. y[co][n] = out_w * delta-t^T + c0[b][co] -> y f32 (aliases ws[0,128MB))
  gemm_tn<2, true, false, false><<<dim3(32, 8, 8), 256, 0, stream>>>(
      w_out, tT, y, c0b, 1024L, nullptr, 0L, nullptr, 0L,
      1.0f, 1024, 4096, 512, 0L, (long)NPIX * DI, (long)1024 * NPIX);
  // 11. BN stats (deterministic)
  stats_kernel<<<1024, 256, 0, stream>>>(y, stats);
  // 12. BN apply + residual
  final_kernel<<<8192, 256, 0, stream>>>(y, x, stats, bn_w, bn_b, out);
}

// Round 4
// 422.166 us; speedup vs baseline: 1.0152x; 1.0152x over previous
//
#include <hip/hip_runtime.h>
#include <cstdint>

typedef unsigned short u16;
typedef __attribute__((ext_vector_type(4))) unsigned short u16x4;
typedef __attribute__((ext_vector_type(8))) short short8;
typedef __attribute__((ext_vector_type(4))) float f32x4;

#define DI 512
#define CIN 1024
#define NPIX 4096   // 64*64
#define MPIX 1024   // 32*32

__device__ __forceinline__ float bf2f(u16 u) {
  union { unsigned int i; float f; } v; v.i = ((unsigned int)u) << 16; return v.f;
}
__device__ __forceinline__ u16 f2bf(float f) {
  union { float f; unsigned int i; } v; v.f = f;
  unsigned int r = v.i + 0x7fffu + ((v.i >> 16) & 1u);
  return (u16)(r >> 16);
}
__device__ __forceinline__ void unpack8(uint4 v, float* f) {
  union { unsigned int i; float f; } u;
  u.i = v.x << 16;          f[0] = u.f;
  u.i = v.x & 0xffff0000u;  f[1] = u.f;
  u.i = v.y << 16;          f[2] = u.f;
  u.i = v.y & 0xffff0000u;  f[3] = u.f;
  u.i = v.z << 16;          f[4] = u.f;
  u.i = v.z & 0xffff0000u;  f[5] = u.f;
  u.i = v.w << 16;          f[6] = u.f;
  u.i = v.w & 0xffff0000u;  f[7] = u.f;
}

// async global->LDS, 16B per lane, wave-uniform LDS base + lane*16
__device__ __forceinline__ void gload16(const u16* g, u16* l) {
  __builtin_amdgcn_global_load_lds(
      (const __attribute__((address_space(1))) void*)g,
      (__attribute__((address_space(3))) void*)l, 16, 0, 0);
}

// ---------------- f32 -> bf16 convert (4 weight tensors in one launch) ----
__global__ __launch_bounds__(256) void cvt4_kernel(
    const float* __restrict__ s0, const float* __restrict__ s1,
    const float* __restrict__ s2, const float* __restrict__ s3,
    u16* __restrict__ d0, u16* __restrict__ d1,
    u16* __restrict__ d2, u16* __restrict__ d3) {
  int i = blockIdx.x * 256 + threadIdx.x;     // 0 .. 4*131072
  int sel = i >> 17;
  int j = i & 131071;
  const float* src = sel == 0 ? s0 : sel == 1 ? s1 : sel == 2 ? s2 : s3;
  u16* dst = sel == 0 ? d0 : sel == 1 ? d1 : sel == 2 ? d2 : d3;
  float4 v = *(const float4*)(src + (long)j * 4);
  u16x4 w;
  w[0] = f2bf(v.x); w[1] = f2bf(v.y); w[2] = f2bf(v.z); w[3] = f2bf(v.w);
  *(u16x4*)(dst + (long)j * 4) = w;
}

// ---------------- x [b][c][n] f32 -> x_T [b][n][c] bf16 ----------------
__global__ __launch_bounds__(256) void transpose_kernel(const float* __restrict__ x,
                                                        u16* __restrict__ xT) {
  __shared__ u16 tile[64][72];
  const int b = blockIdx.z;
  const int n0 = blockIdx.x * 64, c0 = blockIdx.y * 64;
  const float* xb = x + (long)b * CIN * NPIX;
  u16* xTb = xT + (long)b * NPIX * CIN;
  const int t = threadIdx.x;
  const int tc = t >> 4, tn = (t & 15) * 4;
  #pragma unroll
  for (int i = 0; i < 4; i++) {
    int c = tc + i * 16;
    float4 v = *(const float4*)(xb + (long)(c0 + c) * NPIX + n0 + tn);
    tile[c][tn + 0] = f2bf(v.x);
    tile[c][tn + 1] = f2bf(v.y);
    tile[c][tn + 2] = f2bf(v.z);
    tile[c][tn + 3] = f2bf(v.w);
  }
  __syncthreads();
  const int tn2 = t >> 4, tc2 = (t & 15) * 4;
  #pragma unroll
  for (int i = 0; i < 4; i++) {
    int n = tn2 + i * 16;
    u16x4 w;
    w[0] = tile[tc2 + 0][n];
    w[1] = tile[tc2 + 1][n];
    w[2] = tile[tc2 + 2][n];
    w[3] = tile[tc2 + 3][n];
    *(u16x4*)(xTb + (long)(n0 + n) * CIN + c0 + tc2) = w;
  }
}

// ---------------- 2x2 maxpool in transposed layout ----------------
__global__ __launch_bounds__(256) void pool_kernel(const u16* __restrict__ xT,
                                                   u16* __restrict__ poolT) {
  const int idx = blockIdx.x * 256 + threadIdx.x;
  const int cc = (idx & 127) * 8;
  const int m = (idx >> 7) & 1023;
  const int b = idx >> 17;
  const int i = m >> 5, j = m & 31;
  const int n1 = (i * 2) * 64 + j * 2;
  const u16* base = xT + (long)b * NPIX * CIN + cc;
  uint4 v0 = *(const uint4*)(base + (long)(n1) * CIN);
  uint4 v1 = *(const uint4*)(base + (long)(n1 + 1) * CIN);
  uint4 v2 = *(const uint4*)(base + (long)(n1 + 64) * CIN);
  uint4 v3 = *(const uint4*)(base + (long)(n1 + 65) * CIN);
  float f0[8], f1[8], f2[8], f3[8];
  unpack8(v0, f0); unpack8(v1, f1); unpack8(v2, f2); unpack8(v3, f3);
  u16 r[8] __attribute__((aligned(16)));
  #pragma unroll
  for (int k = 0; k < 8; k++) {
    float mx = fmaxf(fmaxf(f0[k], f1[k]), fmaxf(f2[k], f3[k]));
    r[k] = f2bf(mx);
  }
  *(uint4*)(poolT + ((long)b * MPIX + m) * CIN + cc) = *(uint4*)r;
}

// ---------------- GEMM: C[M][N] = A[M][K] * B[N][K]^T ----
// global_load_lds staging, linear LDS [128][64] bf16, XOR-swizzled 16B slots:
//   LDS[row][slot] = G[row][slot ^ (row&7)]   (slot = 16B chunk, 8 per row)
// OM: 0 = bf16 plain, 1 = bf16 transposed [N][M], 2 = f32 plain.
template<int OM, bool HAS_BIAS, bool HAS_CS, bool HAS_SHIFT>
__global__ __launch_bounds__(256)
void gemm_tn(const u16* __restrict__ A, const u16* __restrict__ B,
             void* __restrict__ Cv,
             const float* __restrict__ bias, long sBias,
             const float* __restrict__ cs, long sCS,
             const float* __restrict__ shift, long sShift,
             float scale, int M, int N, int K, long sA, long sB, long sC)
{
  A += blockIdx.z * sA;
  B += blockIdx.z * sB;
  if (HAS_BIAS) bias += blockIdx.z * sBias;
  if (HAS_CS) cs += blockIdx.z * sCS;
  if (HAS_SHIFT) shift += blockIdx.z * sShift;
  const int bm = blockIdx.y * 128;
  const int bn = blockIdx.x * 128;
  __shared__ __align__(16) u16 As[128 * 64];
  __shared__ __align__(16) u16 Bs[128 * 64];
  const int tid = threadIdx.x;
  const int lane = tid & 63;
  const int wave = tid >> 6;
  const int wm = (wave >> 1) * 64;
  const int wn = (wave & 1) * 64;
  const int lr = lane & 15;          // frag row (A) / col (B,D)
  const int q  = lane >> 4;          // 16B slot quarter within k
  const int sxor = lane & 7;         // row&7 of the fragment row
  f32x4 acc[4][4] = {};

  // staging addresses: wave w, call i covers rows 32w+8i..+8, lane l -> row
  // 32w+8i+(l>>3), slot l&7; global chunk = (l&7)^(l>>3)  [= slot^(row&7)]
  const int swz = ((lane & 7) ^ (lane >> 3)) * 8;
  const long grow = 32 * wave + (lane >> 3);
  const u16* Ag = A + ((long)bm + grow) * K + swz;
  const u16* Bg = B + ((long)bn + grow) * K + swz;

  for (int kt = 0; kt < K; kt += 64) {
    __syncthreads();
    #pragma unroll
    for (int i = 0; i < 4; i++) {
      gload16(Ag + (long)(8 * i) * K + kt, &As[(wave * 4 + i) * 512]);
      gload16(Bg + (long)(8 * i) * K + kt, &Bs[(wave * 4 + i) * 512]);
    }
    __syncthreads();
    #pragma unroll
    for (int kk = 0; kk < 2; kk++) {
      short8 av[4], bv[4];
      #pragma unroll
      for (int mi = 0; mi < 4; mi++)
        av[mi] = *(const short8*)&As[(wm + mi * 16 + lr) * 64 +
                                     (((kk << 2) + q) ^ sxor) * 8];
      #pragma unroll
      for (int ni = 0; ni < 4; ni++)
        bv[ni] = *(const short8*)&Bs[(wn + ni * 16 + lr) * 64 +
                                     (((kk << 2) + q) ^ sxor) * 8];
      #pragma unroll
      for (int mi = 0; mi < 4; mi++) {
        #pragma unroll
        for (int ni = 0; ni < 4; ni++)
          acc[mi][ni] = __builtin_amdgcn_mfma_f32_16x16x32_bf16(
              av[mi], bv[ni], acc[mi][ni], 0, 0, 0);
      }
    }
  }

  const int dr = (lane >> 4) * 4;
  #pragma unroll
  for (int mi = 0; mi < 4; mi++) {
    const int rowb = bm + wm + mi * 16 + dr;
    float bvs[4] = {0.f, 0.f, 0.f, 0.f};
    float shv[4] = {0.f, 0.f, 0.f, 0.f};
    if (HAS_BIAS) {
      #pragma unroll
      for (int r = 0; r < 4; r++) bvs[r] = bias[rowb + r];
    }
    if (HAS_SHIFT) {
      #pragma unroll
      for (int r = 0; r < 4; r++) shv[r] = shift[rowb + r];
    }
    #pragma unroll
    for (int ni = 0; ni < 4; ni++) {
      const int col = bn + wn + ni * 16 + lr;
      const float csv = HAS_CS ? cs[col] : 1.0f;
      float v[4];
      #pragma unroll
      for (int r = 0; r < 4; r++) {
        float t = acc[mi][ni][r] * scale;
        if (HAS_CS) t *= csv;
        if (HAS_SHIFT) t -= shv[r];
        if (HAS_BIAS) t += bvs[r];
        v[r] = t;
      }
      if (OM == 1) {
        u16* C = (u16*)Cv + blockIdx.z * sC;
        u16x4 w;
        #pragma unroll
        for (int r = 0; r < 4; r++) w[r] = f2bf(v[r]);
        *(u16x4*)(C + (long)col * M + rowb) = w;
      } else if (OM == 0) {
        u16* C = (u16*)Cv + blockIdx.z * sC;
        #pragma unroll
        for (int r = 0; r < 4; r++)
          C[(long)(rowb + r) * N + col] = f2bf(v[r]);
      } else {
        float* C = (float*)Cv + blockIdx.z * sC;
        #pragma unroll
        for (int r = 0; r < 4; r++)
          C[(long)(rowb + r) * N + col] = v[r];
      }
    }
  }
}

// ---------------- row softmax (unnormalized): one WAVE per row of 1024 ----
__global__ __launch_bounds__(256) void softmax_kernel(const u16* __restrict__ s,
                                                      u16* __restrict__ e_out,
                                                      float* __restrict__ inv_out) {
  const int row = blockIdx.x * 4 + (threadIdx.x >> 6);
  const int lane = threadIdx.x & 63;
  const long base = (long)row * MPIX + lane * 16;
  uint4 va = *(const uint4*)(s + base);
  uint4 vb = *(const uint4*)(s + base + 8);
  float f[16];
  unpack8(va, f); unpack8(vb, f + 8);
  float mx = f[0];
  #pragma unroll
  for (int j = 1; j < 16; j++) mx = fmaxf(mx, f[j]);
  #pragma unroll
  for (int off = 32; off > 0; off >>= 1) mx = fmaxf(mx, __shfl_xor(mx, off));
  float e[16], sum = 0.f;
  #pragma unroll
  for (int j = 0; j < 16; j++) { e[j] = expf(f[j] - mx); sum += e[j]; }
  #pragma unroll
  for (int off = 32; off > 0; off >>= 1) sum += __shfl_xor(sum, off);
  if (lane == 0) inv_out[row] = 1.0f / sum;
  u16 r[16] __attribute__((aligned(16)));
  #pragma unroll
  for (int j = 0; j < 16; j++) r[j] = f2bf(e[j]);
  *(uint4*)(e_out + base) = *(uint4*)r;
  *(uint4*)(e_out + base + 8) = *(uint4*)(r + 8);
}

// ---------------- gbar[b][d] = mean over m of g_n[b][d][:] ----------------
__global__ __launch_bounds__(256) void gbar_kernel(const u16* __restrict__ g_n,
                                                   float* __restrict__ gbar) {
  const int row = blockIdx.x * 4 + (threadIdx.x >> 6);   // 0..4095 = b*512+d
  const int lane = threadIdx.x & 63;
  const long base = (long)row * MPIX + lane * 16;
  uint4 va = *(const uint4*)(g_n + base);
  uint4 vb = *(const uint4*)(g_n + base + 8);
  float f[16];
  unpack8(va, f); unpack8(vb, f + 8);
  float s = 0.f;
  #pragma unroll
  for (int j = 0; j < 16; j++) s += f[j];
  #pragma unroll
  for (int off = 32; off > 0; off >>= 1) s += __shfl_xor(s, off);
  if (lane == 0) gbar[row] = s * (1.0f / 1024.0f);
}

// ------- c0[b][c] = out_b[c] + sum_d out_w_f32[c][d]*gbar[b][d] ----------
__global__ __launch_bounds__(256) void c0_kernel(const float* __restrict__ out_w,
                                                 const float* __restrict__ out_b,
                                                 const float* __restrict__ gbar,
                                                 float* __restrict__ c0) {
  const int idx = blockIdx.x * 4 + (threadIdx.x >> 6);   // 0..8191 = b*1024+c
  const int lane = threadIdx.x & 63;
  const int b = idx >> 10, c = idx & 1023;
  const int d0 = lane * 8;
  float4 w0 = *(const float4*)(out_w + (long)c * DI + d0);
  float4 w1 = *(const float4*)(out_w + (long)c * DI + d0 + 4);
  float4 g0 = *(const float4*)(gbar + (long)b * DI + d0);
  float4 g1 = *(const float4*)(gbar + (long)b * DI + d0 + 4);
  float s = w0.x * g0.x + w0.y * g0.y + w0.z * g0.z + w0.w * g0.w
          + w1.x * g1.x + w1.y * g1.y + w1.z * g1.z + w1.w * g1.w;
  #pragma unroll
  for (int off = 32; off > 0; off >>= 1) s += __shfl_xor(s, off);
  if (lane == 0) c0[idx] = out_b[c] + s;
}

// ---------------- BN stats on f32 y: one block per channel ---------------
__global__ __launch_bounds__(256) void stats_kernel(const float* __restrict__ y,
                                                    float* __restrict__ stats) {
  const int co = blockIdx.x;
  const int t = threadIdx.x;
  float s = 0.f, s2 = 0.f;
  for (int b = 0; b < 8; b++) {
    const long base = ((long)b * 1024 + co) * 4096;
    #pragma unroll
    for (int i = 0; i < 4; i++) {
      float4 v = *(const float4*)(y + base + (long)(i * 256 + t) * 4);
      s += v.x + v.y + v.z + v.w;
      s2 += v.x * v.x + v.y * v.y + v.z * v.z + v.w * v.w;
    }
  }
  #pragma unroll
  for (int off = 32; off > 0; off >>= 1) {
    s += __shfl_xor(s, off);
    s2 += __shfl_xor(s2, off);
  }
  __shared__ float rs[4], rq[4];
  if ((t & 63) == 0) { rs[t >> 6] = s; rq[t >> 6] = s2; }
  __syncthreads();
  if (t == 0) {
    stats[co] = rs[0] + rs[1] + rs[2] + rs[3];
    stats[1024 + co] = rq[0] + rq[1] + rq[2] + rq[3];
  }
}

// ---------------- BN apply + residual (f32 y) ----------------
__global__ __launch_bounds__(256) void final_kernel(const float* __restrict__ y,
    const float* __restrict__ x, const float* __restrict__ stats,
    const float* __restrict__ bnw, const float* __restrict__ bnb,
    float* __restrict__ out) {
  const int bc = blockIdx.x;
  const int co = bc & 1023;
  const float mean = stats[co] * (1.0f / 32768.0f);
  const float var = stats[1024 + co] * (1.0f / 32768.0f) - mean * mean;
  const float inv = rsqrtf(var + 1e-5f) * bnw[co];
  const float add = bnb[co] - mean * inv;
  const long base = (long)bc * 4096;
  const int t = threadIdx.x;
  #pragma unroll
  for (int i = 0; i < 4; i++) {
    const long off = base + (long)(i * 256 + t) * 4;
    float4 v = *(const float4*)(y + off);
    const float4 xv = *(const float4*)(x + off);
    float4 o;
    o.x = v.x * inv + add + xv.x;
    o.y = v.y * inv + add + xv.y;
    o.z = v.z * inv + add + xv.z;
    o.w = v.w * inv + add + xv.w;
    *(float4*)(out + off) = o;
  }
}

extern "C" void kernel_launch(void* const* d_in, const int* in_sizes, int n_in,
                              void* d_out, int out_size, void* d_ws, size_t ws_size,
                              hipStream_t stream) {
  (void)in_sizes; (void)n_in; (void)out_size; (void)ws_size;
  const float* x       = (const float*)d_in[0];
  const float* theta_w = (const float*)d_in[1];
  const float* theta_b = (const float*)d_in[2];
  const float* phi_w   = (const float*)d_in[3];
  const float* phi_b   = (const float*)d_in[4];
  const float* g_w     = (const float*)d_in[5];
  const float* g_b     = (const float*)d_in[6];
  const float* out_w   = (const float*)d_in[7];
  const float* out_b   = (const float*)d_in[8];
  const float* bn_w    = (const float*)d_in[9];
  const float* bn_b    = (const float*)d_in[10];
  float* out = (float*)d_out;
  char* ws = (char*)d_ws;
  const size_t MB = 1024 * 1024;

  // workspace layout
  u16* xT     = (u16*)(ws + 0 * MB);       // 64MB; later: e (softmax out); later: y f32 [0,128MB)
  u16* poolT  = (u16*)(ws + 64 * MB);      // 16MB
  u16* w_th   = (u16*)(ws + 80 * MB);      // 1MB
  u16* w_ph   = (u16*)(ws + 81 * MB);      // 1MB
  u16* w_g    = (u16*)(ws + 82 * MB);      // 1MB
  u16* thetaT = (u16*)(ws + 84 * MB);      // 32MB
  u16* phiT   = (u16*)(ws + 116 * MB);     // 8MB
  u16* g_n    = (u16*)(ws + 124 * MB);     // 8MB
  u16* scores = (u16*)(ws + 132 * MB);     // 64MB
  u16* tT     = (u16*)(ws + 196 * MB);     // 32MB (delta-t bf16)
  u16* w_out  = (u16*)(ws + 228 * MB);     // 1MB
  float* inv_s = (float*)(ws + 229 * MB);            // 128KB
  float* gbar  = (float*)(ws + 229 * MB + 131072);   // 16KB
  float* c0b   = (float*)(ws + 229 * MB + 147456);   // 32KB
  float* stats = (float*)(ws + 229 * MB + 180224);   // 8KB
  u16* e = xT;                // alias: x_T dead after theta GEMM
  float* y = (float*)ws;      // alias [0,128MB): all dead before y-GEMM

  // 1. weights -> bf16 (single launch)
  cvt4_kernel<<<2048, 256, 0, stream>>>(theta_w, phi_w, g_w, out_w,
                                        w_th, w_ph, w_g, w_out);
  // 2. x -> x_T bf16 ; 3. pool
  transpose_kernel<<<dim3(64, 16, 8), 256, 0, stream>>>(x, xT);
  pool_kernel<<<4096, 256, 0, stream>>>(xT, poolT);
  // 4. theta -> theta_T [b][4096][512]
  gemm_tn<1, true, false, false><<<dim3(32, 4, 8), 256, 0, stream>>>(
      w_th, xT, thetaT, theta_b, 0L, nullptr, 0L, nullptr, 0L,
      1.0f, 512, 4096, 1024, 0L, (long)NPIX * CIN, (long)NPIX * DI);
  // 5. phi -> phi_T [b][1024][512]
  gemm_tn<1, true, false, false><<<dim3(8, 4, 8), 256, 0, stream>>>(
      w_ph, poolT, phiT, phi_b, 0L, nullptr, 0L, nullptr, 0L,
      1.0f, 512, 1024, 1024, 0L, (long)MPIX * CIN, (long)MPIX * DI);
  // 6. g -> g_n [b][512][1024]
  gemm_tn<0, true, false, false><<<dim3(8, 4, 8), 256, 0, stream>>>(
      w_g, poolT, g_n, g_b, 0L, nullptr, 0L, nullptr, 0L,
      1.0f, 512, 1024, 1024, 0L, (long)MPIX * CIN, (long)DI * MPIX);
  // 6b. gbar[b][d] ; c0[b][c] (f32 path for the constant part of t)
  gbar_kernel<<<1024, 256, 0, stream>>>(g_n, gbar);
  c0_kernel<<<2048, 256, 0, stream>>>(out_w, out_b, gbar, c0b);
  // 7. scores[n][m] = theta_T * phi_T^T, scaled; bf16 [b][4096][1024]
  gemm_tn<0, false, false, false><<<dim3(8, 32, 8), 256, 0, stream>>>(
      thetaT, phiT, scores, nullptr, 0L, nullptr, 0L, nullptr, 0L,
      0.044194173824159216f, 4096, 1024, 512,
      (long)NPIX * DI, (long)MPIX * DI, (long)NPIX * MPIX);
  // 8. unnormalized softmax rows -> e (aliases xT), inv_s[b*4096+n]
  softmax_kernel<<<8192, 256, 0, stream>>>(scores, e, inv_s);
  // 9. delta-t[d][n] = (g_n * e^T)*inv_s[n] - gbar[d] -> tT bf16 [b][4096][512]
  gemm_tn<1, false, true, true><<<dim3(32, 4, 8), 256, 0, stream>>>(
      g_n, e, tT, nullptr, 0L, inv_s, 4096L, gbar, 512L,
      1.0f, 512, 4096, 1024,
      (long)DI * MPIX, (long)NPIX * MPIX, (long)NPIX * DI);
  // 10. y[co][n] = out_w * delta-t^T + c0[b][co] -> y f32 (aliases ws[0,128MB))
  gemm_tn<2, true, false, false><<<dim3(32, 8, 8), 256, 0, stream>>>(
      w_out, tT, y, c0b, 1024L, nullptr, 0L, nullptr, 0L,
      1.0f, 1024, 4096, 512, 0L, (long)NPIX * DI, (long)1024 * NPIX);
  // 11. BN stats (deterministic)
  stats_kernel<<<1024, 256, 0, stream>>>(y, stats);
  // 12. BN apply + residual
  final_kernel<<<8192, 256, 0, stream>>>(y, x, stats, bn_w, bn_b, out);
}

// Round 5
// 380.217 us; speedup vs baseline: 1.1272x; 1.1103x over previous
//
#include <hip/hip_runtime.h>
#include <cstdint>

typedef unsigned short u16;
typedef __attribute__((ext_vector_type(4))) unsigned short u16x4;
typedef __attribute__((ext_vector_type(8))) short short8;
typedef __attribute__((ext_vector_type(4))) float f32x4;

#define DI 512
#define CIN 1024
#define NPIX 4096   // 64*64
#define MPIX 1024   // 32*32

__device__ __forceinline__ float bf2f(u16 u) {
  union { unsigned int i; float f; } v; v.i = ((unsigned int)u) << 16; return v.f;
}
__device__ __forceinline__ u16 f2bf(float f) {
  union { float f; unsigned int i; } v; v.f = f;
  unsigned int r = v.i + 0x7fffu + ((v.i >> 16) & 1u);
  return (u16)(r >> 16);
}
__device__ __forceinline__ void unpack8(uint4 v, float* f) {
  union { unsigned int i; float f; } u;
  u.i = v.x << 16;          f[0] = u.f;
  u.i = v.x & 0xffff0000u;  f[1] = u.f;
  u.i = v.y << 16;          f[2] = u.f;
  u.i = v.y & 0xffff0000u;  f[3] = u.f;
  u.i = v.z << 16;          f[4] = u.f;
  u.i = v.z & 0xffff0000u;  f[5] = u.f;
  u.i = v.w << 16;          f[6] = u.f;
  u.i = v.w & 0xffff0000u;  f[7] = u.f;
}

// async global->LDS, 16B per lane, wave-uniform LDS base + lane*16
__device__ __forceinline__ void gload16(const u16* g, u16* l) {
  __builtin_amdgcn_global_load_lds(
      (const __attribute__((address_space(1))) void*)g,
      (__attribute__((address_space(3))) void*)l, 16, 0, 0);
}

// ---------------- f32 -> bf16 convert (4 weight tensors in one launch) ----
__global__ __launch_bounds__(256) void cvt4_kernel(
    const float* __restrict__ s0, const float* __restrict__ s1,
    const float* __restrict__ s2, const float* __restrict__ s3,
    u16* __restrict__ d0, u16* __restrict__ d1,
    u16* __restrict__ d2, u16* __restrict__ d3) {
  int i = blockIdx.x * 256 + threadIdx.x;     // 0 .. 4*131072
  int sel = i >> 17;
  int j = i & 131071;
  const float* src = sel == 0 ? s0 : sel == 1 ? s1 : sel == 2 ? s2 : s3;
  u16* dst = sel == 0 ? d0 : sel == 1 ? d1 : sel == 2 ? d2 : d3;
  float4 v = *(const float4*)(src + (long)j * 4);
  u16x4 w;
  w[0] = f2bf(v.x); w[1] = f2bf(v.y); w[2] = f2bf(v.z); w[3] = f2bf(v.w);
  *(u16x4*)(dst + (long)j * 4) = w;
}

// ---------------- x [b][c][n] f32 -> x_T [b][n][c] bf16 ----------------
__global__ __launch_bounds__(256) void transpose_kernel(const float* __restrict__ x,
                                                        u16* __restrict__ xT) {
  __shared__ u16 tile[64][72];
  const int b = blockIdx.z;
  const int n0 = blockIdx.x * 64, c0 = blockIdx.y * 64;
  const float* xb = x + (long)b * CIN * NPIX;
  u16* xTb = xT + (long)b * NPIX * CIN;
  const int t = threadIdx.x;
  const int tc = t >> 4, tn = (t & 15) * 4;
  #pragma unroll
  for (int i = 0; i < 4; i++) {
    int c = tc + i * 16;
    float4 v = *(const float4*)(xb + (long)(c0 + c) * NPIX + n0 + tn);
    tile[c][tn + 0] = f2bf(v.x);
    tile[c][tn + 1] = f2bf(v.y);
    tile[c][tn + 2] = f2bf(v.z);
    tile[c][tn + 3] = f2bf(v.w);
  }
  __syncthreads();
  const int tn2 = t >> 4, tc2 = (t & 15) * 4;
  #pragma unroll
  for (int i = 0; i < 4; i++) {
    int n = tn2 + i * 16;
    u16x4 w;
    w[0] = tile[tc2 + 0][n];
    w[1] = tile[tc2 + 1][n];
    w[2] = tile[tc2 + 2][n];
    w[3] = tile[tc2 + 3][n];
    *(u16x4*)(xTb + (long)(n0 + n) * CIN + c0 + tc2) = w;
  }
}

// ---------------- 2x2 maxpool in transposed layout ----------------
__global__ __launch_bounds__(256) void pool_kernel(const u16* __restrict__ xT,
                                                   u16* __restrict__ poolT) {
  const int idx = blockIdx.x * 256 + threadIdx.x;
  const int cc = (idx & 127) * 8;
  const int m = (idx >> 7) & 1023;
  const int b = idx >> 17;
  const int i = m >> 5, j = m & 31;
  const int n1 = (i * 2) * 64 + j * 2;
  const u16* base = xT + (long)b * NPIX * CIN + cc;
  uint4 v0 = *(const uint4*)(base + (long)(n1) * CIN);
  uint4 v1 = *(const uint4*)(base + (long)(n1 + 1) * CIN);
  uint4 v2 = *(const uint4*)(base + (long)(n1 + 64) * CIN);
  uint4 v3 = *(const uint4*)(base + (long)(n1 + 65) * CIN);
  float f0[8], f1[8], f2[8], f3[8];
  unpack8(v0, f0); unpack8(v1, f1); unpack8(v2, f2); unpack8(v3, f3);
  u16 r[8] __attribute__((aligned(16)));
  #pragma unroll
  for (int k = 0; k < 8; k++) {
    float mx = fmaxf(fmaxf(f0[k], f1[k]), fmaxf(f2[k], f3[k]));
    r[k] = f2bf(mx);
  }
  *(uint4*)(poolT + ((long)b * MPIX + m) * CIN + cc) = *(uint4*)r;
}

// ---------------- GEMM: C[M][N] = A[M][K] * B[N][K]^T ----
// global_load_lds staging, linear LDS [128][64] bf16, XOR-swizzled 16B slots:
//   LDS[row][slot] = G[row][slot ^ (row&7)]
// OM: 0 = bf16 plain, 1 = bf16 transposed [N][M], 2 = f32 plain.
// HAS_EXP: v = exp(acc*scale); also writes per-block row-sums of v to
//          psum_out[(z*gridX + x)*4096 + row] (deterministic).
template<int OM, bool HAS_BIAS, bool HAS_CS, bool HAS_SHIFT, bool HAS_EXP>
__global__ __launch_bounds__(256)
void gemm_tn(const u16* __restrict__ A, const u16* __restrict__ B,
             void* __restrict__ Cv,
             const float* __restrict__ bias, long sBias,
             const float* __restrict__ cs, long sCS,
             const float* __restrict__ shift, long sShift,
             float* __restrict__ psum_out,
             float scale, int M, int N, int K, long sA, long sB, long sC)
{
  A += blockIdx.z * sA;
  B += blockIdx.z * sB;
  if (HAS_BIAS) bias += blockIdx.z * sBias;
  if (HAS_CS) cs += blockIdx.z * sCS;
  if (HAS_SHIFT) shift += blockIdx.z * sShift;
  const int bm = blockIdx.y * 128;
  const int bn = blockIdx.x * 128;
  __shared__ __align__(16) u16 As[128 * 64];
  __shared__ __align__(16) u16 Bs[128 * 64];
  __shared__ float psum[2][128];
  const int tid = threadIdx.x;
  const int lane = tid & 63;
  const int wave = tid >> 6;
  const int wm = (wave >> 1) * 64;
  const int wn = (wave & 1) * 64;
  const int lr = lane & 15;          // frag row (A) / col (B,D)
  const int q  = lane >> 4;          // 16B slot quarter within k
  const int sxor = lane & 7;
  f32x4 acc[4][4] = {};

  const int swz = ((lane & 7) ^ (lane >> 3)) * 8;
  const long grow = 32 * wave + (lane >> 3);
  const u16* Ag = A + ((long)bm + grow) * K + swz;
  const u16* Bg = B + ((long)bn + grow) * K + swz;

  for (int kt = 0; kt < K; kt += 64) {
    __syncthreads();
    #pragma unroll
    for (int i = 0; i < 4; i++) {
      gload16(Ag + (long)(8 * i) * K + kt, &As[(wave * 4 + i) * 512]);
      gload16(Bg + (long)(8 * i) * K + kt, &Bs[(wave * 4 + i) * 512]);
    }
    __syncthreads();
    #pragma unroll
    for (int kk = 0; kk < 2; kk++) {
      short8 av[4], bv[4];
      #pragma unroll
      for (int mi = 0; mi < 4; mi++)
        av[mi] = *(const short8*)&As[(wm + mi * 16 + lr) * 64 +
                                     (((kk << 2) + q) ^ sxor) * 8];
      #pragma unroll
      for (int ni = 0; ni < 4; ni++)
        bv[ni] = *(const short8*)&Bs[(wn + ni * 16 + lr) * 64 +
                                     (((kk << 2) + q) ^ sxor) * 8];
      #pragma unroll
      for (int mi = 0; mi < 4; mi++) {
        #pragma unroll
        for (int ni = 0; ni < 4; ni++)
          acc[mi][ni] = __builtin_amdgcn_mfma_f32_16x16x32_bf16(
              av[mi], bv[ni], acc[mi][ni], 0, 0, 0);
      }
    }
  }

  const int dr = (lane >> 4) * 4;
  float rowsum[4][4];
  if (HAS_EXP) {
    #pragma unroll
    for (int mi = 0; mi < 4; mi++)
      #pragma unroll
      for (int r = 0; r < 4; r++) rowsum[mi][r] = 0.f;
  }
  #pragma unroll
  for (int mi = 0; mi < 4; mi++) {
    const int rowb = bm + wm + mi * 16 + dr;
    float bvs[4] = {0.f, 0.f, 0.f, 0.f};
    float shv[4] = {0.f, 0.f, 0.f, 0.f};
    if (HAS_BIAS) {
      #pragma unroll
      for (int r = 0; r < 4; r++) bvs[r] = bias[rowb + r];
    }
    if (HAS_SHIFT) {
      #pragma unroll
      for (int r = 0; r < 4; r++) shv[r] = shift[rowb + r];
    }
    #pragma unroll
    for (int ni = 0; ni < 4; ni++) {
      const int col = bn + wn + ni * 16 + lr;
      const float csv = HAS_CS ? cs[col] : 1.0f;
      float v[4];
      #pragma unroll
      for (int r = 0; r < 4; r++) {
        float t = acc[mi][ni][r] * scale;
        if (HAS_CS) t *= csv;
        if (HAS_SHIFT) t -= shv[r];
        if (HAS_BIAS) t += bvs[r];
        if (HAS_EXP) { t = expf(t); rowsum[mi][r] += t; }
        v[r] = t;
      }
      if (OM == 1) {
        u16* C = (u16*)Cv + blockIdx.z * sC;
        u16x4 w;
        #pragma unroll
        for (int r = 0; r < 4; r++) w[r] = f2bf(v[r]);
        *(u16x4*)(C + (long)col * M + rowb) = w;
      } else if (OM == 0) {
        u16* C = (u16*)Cv + blockIdx.z * sC;
        #pragma unroll
        for (int r = 0; r < 4; r++)
          C[(long)(rowb + r) * N + col] = f2bf(v[r]);
      } else {
        float* C = (float*)Cv + blockIdx.z * sC;
        #pragma unroll
        for (int r = 0; r < 4; r++)
          C[(long)(rowb + r) * N + col] = v[r];
      }
    }
  }
  if (HAS_EXP) {
    // sum across the 16 lanes sharing the same rows (lane bits 0-3 vary col)
    #pragma unroll
    for (int msk = 1; msk < 16; msk <<= 1)
      #pragma unroll
      for (int mi = 0; mi < 4; mi++)
        #pragma unroll
        for (int r = 0; r < 4; r++)
          rowsum[mi][r] += __shfl_xor(rowsum[mi][r], msk);
    if ((lane & 15) == 0) {
      #pragma unroll
      for (int mi = 0; mi < 4; mi++)
        #pragma unroll
        for (int r = 0; r < 4; r++)
          psum[wave & 1][wm + mi * 16 + dr + r] = rowsum[mi][r];
    }
    __syncthreads();
    if (tid < 128)
      psum_out[((long)blockIdx.z * gridDim.x + blockIdx.x) * 4096 + bm + tid] =
          psum[0][tid] + psum[1][tid];
  }
}

// ---------------- inv[b][n] = 1 / sum_x partial[b][x][n] ----------------
__global__ __launch_bounds__(256) void inv_kernel(const float* __restrict__ partial,
                                                  float* __restrict__ inv) {
  const int idx = blockIdx.x * 256 + threadIdx.x;   // b*4096+n
  const int b = idx >> 12, n = idx & 4095;
  const float* p = partial + (long)b * 32768 + n;
  float s = 0.f;
  #pragma unroll
  for (int x = 0; x < 8; x++) s += p[(long)x * 4096];
  inv[idx] = 1.0f / s;
}

// ---------------- gbar[b][d] = mean over m of g_n[b][d][:] ----------------
__global__ __launch_bounds__(256) void gbar_kernel(const u16* __restrict__ g_n,
                                                   float* __restrict__ gbar) {
  const int row = blockIdx.x * 4 + (threadIdx.x >> 6);   // 0..4095 = b*512+d
  const int lane = threadIdx.x & 63;
  const long base = (long)row * MPIX + lane * 16;
  uint4 va = *(const uint4*)(g_n + base);
  uint4 vb = *(const uint4*)(g_n + base + 8);
  float f[16];
  unpack8(va, f); unpack8(vb, f + 8);
  float s = 0.f;
  #pragma unroll
  for (int j = 0; j < 16; j++) s += f[j];
  #pragma unroll
  for (int off = 32; off > 0; off >>= 1) s += __shfl_xor(s, off);
  if (lane == 0) gbar[row] = s * (1.0f / 1024.0f);
}

// ------- c0[b][c] = out_b[c] + sum_d out_w_f32[c][d]*gbar[b][d] ----------
__global__ __launch_bounds__(256) void c0_kernel(const float* __restrict__ out_w,
                                                 const float* __restrict__ out_b,
                                                 const float* __restrict__ gbar,
                                                 float* __restrict__ c0) {
  const int idx = blockIdx.x * 4 + (threadIdx.x >> 6);   // 0..8191 = b*1024+c
  const int lane = threadIdx.x & 63;
  const int b = idx >> 10, c = idx & 1023;
  const int d0 = lane * 8;
  float4 w0 = *(const float4*)(out_w + (long)c * DI + d0);
  float4 w1 = *(const float4*)(out_w + (long)c * DI + d0 + 4);
  float4 g0 = *(const float4*)(gbar + (long)b * DI + d0);
  float4 g1 = *(const float4*)(gbar + (long)b * DI + d0 + 4);
  float s = w0.x * g0.x + w0.y * g0.y + w0.z * g0.z + w0.w * g0.w
          + w1.x * g1.x + w1.y * g1.y + w1.z * g1.z + w1.w * g1.w;
  #pragma unroll
  for (int off = 32; off > 0; off >>= 1) s += __shfl_xor(s, off);
  if (lane == 0) c0[idx] = out_b[c] + s;
}

// ------ BN stats from bf16 delta-y and c0: y = c0[b][c] + dy ------------
// S  = 4096*sum_b c0 + sum(dy)
// S2 = 4096*sum_b c0^2 + 2*sum_b c0*(sum_n dy) + sum(dy^2)
__global__ __launch_bounds__(256) void stats_kernel(const u16* __restrict__ dy,
                                                    const float* __restrict__ c0,
                                                    float* __restrict__ stats) {
  const int co = blockIdx.x;
  const int t = threadIdx.x;
  float sd = 0.f, sd2 = 0.f, sbc = 0.f;
  for (int b = 0; b < 8; b++) {
    const long base = ((long)b * 1024 + co) * 4096;
    float pb = 0.f, pb2 = 0.f;
    #pragma unroll
    for (int i = 0; i < 2; i++) {
      uint4 v = *(const uint4*)(dy + base + (long)(i * 256 + t) * 8);
      float f[8]; unpack8(v, f);
      #pragma unroll
      for (int k = 0; k < 8; k++) { pb += f[k]; pb2 += f[k] * f[k]; }
    }
    sd += pb; sd2 += pb2;
    sbc += c0[b * 1024 + co] * pb;
  }
  #pragma unroll
  for (int off = 32; off > 0; off >>= 1) {
    sd += __shfl_xor(sd, off);
    sd2 += __shfl_xor(sd2, off);
    sbc += __shfl_xor(sbc, off);
  }
  __shared__ float rs[4], rq[4], rb[4];
  if ((t & 63) == 0) { rs[t >> 6] = sd; rq[t >> 6] = sd2; rb[t >> 6] = sbc; }
  __syncthreads();
  if (t == 0) {
    float sdT = rs[0] + rs[1] + rs[2] + rs[3];
    float sd2T = rq[0] + rq[1] + rq[2] + rq[3];
    float sbcT = rb[0] + rb[1] + rb[2] + rb[3];
    float sc0 = 0.f, sc02 = 0.f;
    #pragma unroll
    for (int b = 0; b < 8; b++) {
      float c = c0[b * 1024 + co];
      sc0 += c; sc02 += c * c;
    }
    stats[co] = 4096.0f * sc0 + sdT;
    stats[1024 + co] = 4096.0f * sc02 + 2.0f * sbcT + sd2T;
  }
}

// ---------------- BN apply + residual (bf16 dy + c0) ----------------
__global__ __launch_bounds__(256) void final_kernel(const u16* __restrict__ dy,
    const float* __restrict__ x, const float* __restrict__ stats,
    const float* __restrict__ c0,
    const float* __restrict__ bnw, const float* __restrict__ bnb,
    float* __restrict__ out) {
  const int bc = blockIdx.x;
  const int co = bc & 1023;
  const float mean = stats[co] * (1.0f / 32768.0f);
  const float var = stats[1024 + co] * (1.0f / 32768.0f) - mean * mean;
  const float inv = rsqrtf(var + 1e-5f) * bnw[co];
  const float addc = bnb[co] - mean * inv + c0[bc] * inv;
  const long base = (long)bc * 4096;
  const int t = threadIdx.x;
  #pragma unroll
  for (int i = 0; i < 2; i++) {
    const long off = base + (long)(i * 256 + t) * 8;
    uint4 v = *(const uint4*)(dy + off);
    float f[8]; unpack8(v, f);
    const float4 x0 = *(const float4*)(x + off);
    const float4 x1 = *(const float4*)(x + off + 4);
    float4 o0, o1;
    o0.x = f[0] * inv + addc + x0.x;
    o0.y = f[1] * inv + addc + x0.y;
    o0.z = f[2] * inv + addc + x0.z;
    o0.w = f[3] * inv + addc + x0.w;
    o1.x = f[4] * inv + addc + x1.x;
    o1.y = f[5] * inv + addc + x1.y;
    o1.z = f[6] * inv + addc + x1.z;
    o1.w = f[7] * inv + addc + x1.w;
    *(float4*)(out + off) = o0;
    *(float4*)(out + off + 4) = o1;
  }
}

extern "C" void kernel_launch(void* const* d_in, const int* in_sizes, int n_in,
                              void* d_out, int out_size, void* d_ws, size_t ws_size,
                              hipStream_t stream) {
  (void)in_sizes; (void)n_in; (void)out_size; (void)ws_size;
  const float* x       = (const float*)d_in[0];
  const float* theta_w = (const float*)d_in[1];
  const float* theta_b = (const float*)d_in[2];
  const float* phi_w   = (const float*)d_in[3];
  const float* phi_b   = (const float*)d_in[4];
  const float* g_w     = (const float*)d_in[5];
  const float* g_b     = (const float*)d_in[6];
  const float* out_w   = (const float*)d_in[7];
  const float* out_b   = (const float*)d_in[8];
  const float* bn_w    = (const float*)d_in[9];
  const float* bn_b    = (const float*)d_in[10];
  float* out = (float*)d_out;
  char* ws = (char*)d_ws;
  const size_t MB = 1024 * 1024;

  // workspace layout
  u16* xT     = (u16*)(ws + 0 * MB);       // 64MB; later: dy bf16 [0,64MB)
  u16* poolT  = (u16*)(ws + 64 * MB);      // 16MB
  u16* w_th   = (u16*)(ws + 80 * MB);      // 1MB
  u16* w_ph   = (u16*)(ws + 81 * MB);      // 1MB
  u16* w_g    = (u16*)(ws + 82 * MB);      // 1MB
  u16* thetaT = (u16*)(ws + 84 * MB);      // 32MB
  u16* phiT   = (u16*)(ws + 116 * MB);     // 8MB
  u16* g_n    = (u16*)(ws + 124 * MB);     // 8MB
  u16* e      = (u16*)(ws + 132 * MB);     // 64MB (exp(scores))
  u16* tT     = (u16*)(ws + 196 * MB);     // 32MB (delta-t bf16)
  u16* w_out  = (u16*)(ws + 228 * MB);     // 1MB
  float* inv_s = (float*)(ws + 229 * MB);            // 128KB
  float* gbar  = (float*)(ws + 229 * MB + 131072);   // 16KB
  float* c0b   = (float*)(ws + 229 * MB + 147456);   // 32KB
  float* stats = (float*)(ws + 229 * MB + 180224);   // 8KB
  float* partial = (float*)(ws + 230 * MB);          // 1MB (8*8*4096 f32)
  u16* dy = xT;               // alias: x_T dead after theta GEMM

  // 1. weights -> bf16 (single launch)
  cvt4_kernel<<<2048, 256, 0, stream>>>(theta_w, phi_w, g_w, out_w,
                                        w_th, w_ph, w_g, w_out);
  // 2. x -> x_T bf16 ; 3. pool
  transpose_kernel<<<dim3(64, 16, 8), 256, 0, stream>>>(x, xT);
  pool_kernel<<<4096, 256, 0, stream>>>(xT, poolT);
  // 4. theta -> theta_T [b][4096][512]
  gemm_tn<1, true, false, false, false><<<dim3(32, 4, 8), 256, 0, stream>>>(
      w_th, xT, thetaT, theta_b, 0L, nullptr, 0L, nullptr, 0L, nullptr,
      1.0f, 512, 4096, 1024, 0L, (long)NPIX * CIN, (long)NPIX * DI);
  // 5. phi -> phi_T [b][1024][512]
  gemm_tn<1, true, false, false, false><<<dim3(8, 4, 8), 256, 0, stream>>>(
      w_ph, poolT, phiT, phi_b, 0L, nullptr, 0L, nullptr, 0L, nullptr,
      1.0f, 512, 1024, 1024, 0L, (long)MPIX * CIN, (long)MPIX * DI);
  // 6. g -> g_n [b][512][1024]
  gemm_tn<0, true, false, false, false><<<dim3(8, 4, 8), 256, 0, stream>>>(
      w_g, poolT, g_n, g_b, 0L, nullptr, 0L, nullptr, 0L, nullptr,
      1.0f, 512, 1024, 1024, 0L, (long)MPIX * CIN, (long)DI * MPIX);
  // 6b. gbar[b][d] ; c0[b][c] (f32 path for the constant part of t)
  gbar_kernel<<<1024, 256, 0, stream>>>(g_n, gbar);
  c0_kernel<<<2048, 256, 0, stream>>>(out_w, out_b, gbar, c0b);
  // 7. e[n][m] = exp(theta_T*phi_T^T * scale) + per-block rowsum partials
  gemm_tn<0, false, false, false, true><<<dim3(8, 32, 8), 256, 0, stream>>>(
      thetaT, phiT, e, nullptr, 0L, nullptr, 0L, nullptr, 0L, partial,
      0.044194173824159216f, 4096, 1024, 512,
      (long)NPIX * DI, (long)MPIX * DI, (long)NPIX * MPIX);
  // 8. inv[b][n] = 1/rowsum
  inv_kernel<<<128, 256, 0, stream>>>(partial, inv_s);
  // 9. delta-t[d][n] = (g_n * e^T)*inv_s[n] - gbar[d] -> tT bf16 [b][4096][512]
  gemm_tn<1, false, true, true, false><<<dim3(32, 4, 8), 256, 0, stream>>>(
      g_n, e, tT, nullptr, 0L, inv_s, 4096L, gbar, 512L, nullptr,
      1.0f, 512, 4096, 1024,
      (long)DI * MPIX, (long)NPIX * MPIX, (long)NPIX * DI);
  // 10. dy[co][n] = out_w * delta-t^T (bf16, no bias) -> dy (aliases xT)
  gemm_tn<0, false, false, false, false><<<dim3(32, 8, 8), 256, 0, stream>>>(
      w_out, tT, dy, nullptr, 0L, nullptr, 0L, nullptr, 0L, nullptr,
      1.0f, 1024, 4096, 512, 0L, (long)NPIX * DI, (long)1024 * NPIX);
  // 11. BN stats from dy + c0 (deterministic)
  stats_kernel<<<1024, 256, 0, stream>>>(dy, c0b, stats);
  // 12. BN apply + residual
  final_kernel<<<8192, 256, 0, stream>>>(dy, x, stats, c0b, bn_w, bn_b, out);
}